// Round 1
// baseline (732.592 us; speedup 1.0000x reference)
//
#include <hip/hip_runtime.h>

#define BB 512
#define LDIM 2713
#define ZDIM 58
#define GDIM 8
#define NLAYER 6
#define FFDIM 2048
#define RNAIN 1018
#define CATDIM 528
#define NCAT 1482    // 1018 rna-folded + 464 flat
#define LQ 679       // ceil(2713/4)

typedef float v2f __attribute__((ext_vector_type(2)));
typedef float f32x4 __attribute__((ext_vector_type(4)));
typedef _Float16 f16x4 __attribute__((ext_vector_type(4)));

// ---------------- ws layout (floats) ----------------
#define OFF_WCATT  0            // WcatT [1482][64]   94848
#define OFF_BPRIME 94848        // bprime[64]

// ============ prep: WcatT + bprime in ONE dispatch ============
// blocks 0..15: TmatT (redundant, in LDS) -> WcatT k-slice
// block 16:     bR -> bprime, plus WcatT flat-part copy rows
__global__ __launch_bounds__(1024) void prep_kernel(
    const float* __restrict__ lin1_w, const float* __restrict__ lin1_b,
    const float* __restrict__ lin2_w, const float* __restrict__ lin2_b,
    const float* __restrict__ c1_w, const float* __restrict__ c1_b,
    float* __restrict__ ws) {
    __shared__ float Tm[16384];            // [n=256][j=64]
    const int t = threadIdx.x;
    float* WcatT = ws + OFF_WCATT;

    if (blockIdx.x == 16) {
        if (t < 64) {                      // bR[m] = lin2_b + lin2 @ lin1_b
            float a = lin2_b[t];
            #pragma unroll 4
            for (int n = 0; n < 256; ++n) a += lin2_w[t * 256 + n] * lin1_b[n];
            Tm[t] = a;
        }
        __syncthreads();
        if (t < 64) {                      // bprime[j] = c1_b + c1[:, :64] @ bR
            float a = c1_b[t];
            #pragma unroll 4
            for (int m = 0; m < 64; ++m) a += c1_w[t * CATDIM + m] * Tm[m];
            ws[OFF_BPRIME + t] = a;
        }
        for (int i = t; i < 464 * 64; i += 1024) {   // flat-part rows of WcatT
            int kk = i >> 6, j = i & 63;
            WcatT[(RNAIN + kk) * 64 + j] = c1_w[j * CATDIM + 64 + kk];
        }
        return;
    }

    // TmatT[n][j] = sum_m c1[j][m] * lin2[m][n]
    for (int i = t; i < 16384; i += 1024) {
        int n = i >> 6, j = i & 63;
        float a = 0.f;
        #pragma unroll 8
        for (int m = 0; m < 64; ++m) a += c1_w[j * CATDIM + m] * lin2_w[m * 256 + n];
        Tm[i] = a;
    }
    __syncthreads();
    // WcatT[k][j] = sum_n TmatT[n][j] * lin1_w[n][k]
    const int k0 = blockIdx.x * 64;
    const int j = t & 63;
    for (int kr = t >> 6; kr < 64; kr += 16) {
        int k = k0 + kr;
        if (k >= RNAIN) break;
        float a = 0.f;
        #pragma unroll 8
        for (int n = 0; n < 256; ++n) a += Tm[n * 64 + j] * lin1_w[n * RNAIN + k];
        WcatT[k * 64 + j] = a;
    }
}

// ============ mega: embed (in-block) -> 6 layers -> head ============
__global__ __launch_bounds__(1024, 8) void mega_kernel(
    const float* __restrict__ drug, const float* __restrict__ chem_w,
    const float* __restrict__ pos_w,
    const float* __restrict__ ff1_w, const float* __restrict__ ff2_w,
    const float* __restrict__ ff1_b,
    const float* __restrict__ qkv_w, const float* __restrict__ qkv_b,
    const float* __restrict__ out_w, const float* __restrict__ out_b,
    const float* __restrict__ ln1_g, const float* __restrict__ ln1_b,
    const float* __restrict__ ff2_b,
    const float* __restrict__ ln2_g, const float* __restrict__ ln2_b,
    const float* __restrict__ rna, const float* __restrict__ WcatT,
    const float* __restrict__ bprime,
    const float* __restrict__ c2_w, const float* __restrict__ c2_b,
    const float* __restrict__ c3_w, const float* __restrict__ c3_b,
    float* __restrict__ out) {
    __shared__ float smem[12864];
    // embed-phase aliases (dead after reduce):
    float* cwl    = smem;           // 5432(+8) chem quarter [i][g]
    float* part_e = smem + 5440;    // 7424 = [w16][z58][g8] (packed 464/wave)
    // main-phase aliases:
    float* xs    = smem;            // 512
    float* qs    = smem + 512;      // 480  [h][60]
    float* ks    = smem + 992;      // 480
    float* vs    = smem + 1472;     // 480
    float* os    = smem + 1952;     // 512  [s][h]
    float* part  = smem + 2464;     // 8192 [w16][64][8]
    float* qkvws = smem + 10656;    // 1152
    float* qkvbs = smem + 11808;    // 144
    float* outws = smem + 11952;    // 384
    float* outbs = smem + 12336;    // 48
    float* l1gs  = smem + 12384;    // 48
    float* l1bs  = smem + 12432;    // 48
    float* l2gs  = smem + 12480;    // 48
    float* l2bs  = smem + 12528;    // 48
    float* f2bs  = smem + 12576;    // 48
    float* h1s   = smem + 12624;    // 64
    float* h2s   = smem + 12688;    // 8

    const int b = blockIdx.x;
    const int t = threadIdx.x;
    const int w = __builtin_amdgcn_readfirstlane(t >> 6);   // wave id 0..15
    const int lane = t & 63;
    const int quad = lane >> 4;
    const int i16 = lane & 15;

    // ---------------- embed: this block's batch, accumulated in registers ----------------
    {
        const int zc = (lane < ZDIM) ? lane : (ZDIM - 1);
        v2f acc0 = {0.f, 0.f}, acc1 = {0.f, 0.f}, acc2 = {0.f, 0.f}, acc3 = {0.f, 0.f};
        for (int q = 0; q < 4; ++q) {
            const int l0 = q * LQ;
            const int nrows = (LDIM - l0 < LQ) ? (LDIM - l0) : LQ;   // 679,679,679,676
            __syncthreads();   // cwl free from previous quarter's readers
            #pragma unroll
            for (int g = 0; g < 8; ++g)
                for (int i = t; i < nrows; i += 1024)
                    cwl[i * 8 + g] = chem_w[g * LDIM + l0 + i];
            __syncthreads();
            const float* dp = drug + (size_t)b * (LDIM * ZDIM) + (size_t)l0 * ZDIM;
            int r0 = w * 43;
            int r1 = (r0 + 43 < nrows) ? (r0 + 43) : nrows;
            int r = r0;
            for (; r + 4 <= r1; r += 4) {
                float d0 = dp[(r + 0) * ZDIM + zc];
                float d1 = dp[(r + 1) * ZDIM + zc];
                float d2 = dp[(r + 2) * ZDIM + zc];
                float d3 = dp[(r + 3) * ZDIM + zc];
                const v2f* c0 = (const v2f*)(cwl + (r + 0) * 8);
                const v2f* c1 = (const v2f*)(cwl + (r + 1) * 8);
                const v2f* c2 = (const v2f*)(cwl + (r + 2) * 8);
                const v2f* c3 = (const v2f*)(cwl + (r + 3) * 8);
                v2f dd;
                dd = (v2f){d0, d0};
                acc0 += c0[0] * dd; acc1 += c0[1] * dd; acc2 += c0[2] * dd; acc3 += c0[3] * dd;
                dd = (v2f){d1, d1};
                acc0 += c1[0] * dd; acc1 += c1[1] * dd; acc2 += c1[2] * dd; acc3 += c1[3] * dd;
                dd = (v2f){d2, d2};
                acc0 += c2[0] * dd; acc1 += c2[1] * dd; acc2 += c2[2] * dd; acc3 += c2[3] * dd;
                dd = (v2f){d3, d3};
                acc0 += c3[0] * dd; acc1 += c3[1] * dd; acc2 += c3[2] * dd; acc3 += c3[3] * dd;
            }
            for (; r < r1; ++r) {
                float d = dp[r * ZDIM + zc];
                const v2f* cc = (const v2f*)(cwl + r * 8);
                v2f dd = {d, d};
                acc0 += cc[0] * dd; acc1 += cc[1] * dd; acc2 += cc[2] * dd; acc3 += cc[3] * dd;
            }
        }
        if (lane < ZDIM) {
            v2f* pr = (v2f*)(part_e + w * 464 + zc * 8);
            pr[0] = acc0; pr[1] = acc1; pr[2] = acc2; pr[3] = acc3;
        }
        __syncthreads();
        if (t < 512) {
            if (t < 464) {
                int z = t >> 3, g = t & 7;
                float s = pos_w[g * ZDIM + z];
                #pragma unroll
                for (int ww = 0; ww < 16; ++ww) s += part_e[ww * 464 + t];
                xs[t] = s;                 // xs overlaps cwl (dead); part_e read-only here
            } else {
                xs[t] = 0.f;               // zero pad rows z=58..63
            }
        }
        __syncthreads();                   // part_e dead after this
    }

    // ---- hoist small per-layer weights (overlaps dead part_e tail) ----
    for (int i = t; i < 1152; i += 1024) qkvws[i] = qkv_w[i];
    if (t < 144) qkvbs[t] = qkv_b[t];
    if (t < 384) outws[t] = out_w[t];
    if (t < 48) {
        outbs[t] = out_b[t];
        l1gs[t] = ln1_g[t]; l1bs[t] = ln1_b[t];
        l2gs[t] = ln2_g[t]; l2bs[t] = ln2_b[t];
        f2bs[t] = ff2_b[t];
    }
    __syncthreads();

    // ---------------- 6 transformer layers ----------------
    for (int li = 0; li < NLAYER; ++li) {
        // qkv projection: thread = (z, h)
        if (t < 464) {
            int z = t >> 3, h = t & 7;
            const float4* xr = (const float4*)(xs + z * 8);
            float4 x0 = xr[0], x1 = xr[1];
            #pragma unroll
            for (int p = 0; p < 3; ++p) {
                int j = p * 8 + h;
                const float4* wr = (const float4*)(qkvws + li * 192 + j * 8);
                float4 w0 = wr[0], w1 = wr[1];
                float a = qkvbs[li * 24 + j]
                        + x0.x * w0.x + x0.y * w0.y + x0.z * w0.z + x0.w * w0.w
                        + x1.x * w1.x + x1.y * w1.y + x1.z * w1.z + x1.w * w1.w;
                float* dst = (p == 0) ? qs : (p == 1) ? ks : vs;
                dst[h * 60 + z] = a;
            }
        }
        __syncthreads();

        // attention (HD=1 rank-1 logits; unshifted softmax exact on LN'd activations)
        if (t < 464) {
            int h = t & 7, s = t >> 3;
            float q = qs[h * 60 + s];
            const float4* kr = (const float4*)(ks + h * 60);
            const float4* vr = (const float4*)(vs + h * 60);
            float sum = 0.f, oa = 0.f;
            #pragma unroll 2
            for (int c = 0; c < 14; ++c) {
                float4 k4 = kr[c], v4 = vr[c];
                float e0 = __expf(q * k4.x); sum += e0; oa += e0 * v4.x;
                float e1 = __expf(q * k4.y); sum += e1; oa += e1 * v4.y;
                float e2 = __expf(q * k4.z); sum += e2; oa += e2 * v4.z;
                float e3 = __expf(q * k4.w); sum += e3; oa += e3 * v4.w;
            }
            {
                const float* kk = ks + h * 60;
                const float* vv = vs + h * 60;
                float e0 = __expf(q * kk[56]); sum += e0; oa += e0 * vv[56];
                float e1 = __expf(q * kk[57]); sum += e1; oa += e1 * vv[57];
            }
            os[t] = oa / sum;
        }
        __syncthreads();

        // out-proj + residual + LN1
        if (t < 464) {
            int z = t >> 3, g = t & 7;
            const float4* orow = (const float4*)(os + z * 8);
            float4 o0 = orow[0], o1 = orow[1];
            const float4* wr = (const float4*)(outws + li * 64 + g * 8);
            float4 w0 = wr[0], w1 = wr[1];
            float a = outbs[li * 8 + g] + xs[t]
                    + o0.x * w0.x + o0.y * w0.y + o0.z * w0.z + o0.w * w0.w
                    + o1.x * w1.x + o1.y * w1.y + o1.z * w1.z + o1.w * w1.w;
            float s8 = a + __shfl_xor(a, 1);
            s8 += __shfl_xor(s8, 2);
            s8 += __shfl_xor(s8, 4);
            float mu = s8 * 0.125f;
            float d = a - mu;
            float vv = d * d;
            vv += __shfl_xor(vv, 1); vv += __shfl_xor(vv, 2); vv += __shfl_xor(vv, 4);
            float inv = rsqrtf(vv * 0.125f + 1e-5f);
            xs[t] = d * inv * l1gs[li * 8 + g] + l1bs[li * 8 + g];
        }
        __syncthreads();

        // ---- FFN via MFMA f16, W frags converted on the fly (RNE casts) ----
        {
            f16x4 xb[4];
            #pragma unroll
            for (int nt = 0; nt < 4; ++nt) {
                if (quad < 2) {
                    const float4* xp = (const float4*)(xs + (nt * 16 + i16) * 8 + quad * 4);
                    float4 xv = *xp;
                    xb[nt][0] = (_Float16)xv.x; xb[nt][1] = (_Float16)xv.y;
                    xb[nt][2] = (_Float16)xv.z; xb[nt][3] = (_Float16)xv.w;
                } else {
                    xb[nt][0] = (_Float16)0.f; xb[nt][1] = (_Float16)0.f;
                    xb[nt][2] = (_Float16)0.f; xb[nt][3] = (_Float16)0.f;
                }
            }
            f32x4 oacc[4];
            #pragma unroll
            for (int nt = 0; nt < 4; ++nt) { oacc[nt][0]=0.f; oacc[nt][1]=0.f; oacc[nt][2]=0.f; oacc[nt][3]=0.f; }

            const float* w1p = ff1_w + ((size_t)li * FFDIM + w * 128) * 8;   // A[m=f][k=g]
            const float* a2p = ff2_w + (size_t)li * GDIM * FFDIM + w * 128;  // A[m=g][k=f]
            const float* b1p = ff1_b + li * FFDIM + w * 128;

            #pragma unroll 2
            for (int ft = 0; ft < 8; ++ft) {
                f16x4 w1f = {};
                if (lane < 32) {
                    f32x4 v = *(const f32x4*)(w1p + (size_t)(ft * 16 + i16) * 8 + quad * 4);
                    w1f[0] = (_Float16)v[0]; w1f[1] = (_Float16)v[1];
                    w1f[2] = (_Float16)v[2]; w1f[3] = (_Float16)v[3];
                }
                f16x4 a2f = {};
                if (i16 < 8) {
                    f32x4 v = *(const f32x4*)(a2p + (size_t)i16 * FFDIM + ft * 16 + quad * 4);
                    a2f[0] = (_Float16)v[0]; a2f[1] = (_Float16)v[1];
                    a2f[2] = (_Float16)v[2]; a2f[3] = (_Float16)v[3];
                }
                f32x4 b1v = *(const f32x4*)(b1p + ft * 16 + quad * 4);
                #pragma unroll
                for (int nt = 0; nt < 4; ++nt) {
                    f32x4 h = b1v;
                    h = __builtin_amdgcn_mfma_f32_16x16x16f16(w1f, xb[nt], h, 0, 0, 0);
                    h[0] = fmaxf(h[0], 0.f); h[1] = fmaxf(h[1], 0.f);
                    h[2] = fmaxf(h[2], 0.f); h[3] = fmaxf(h[3], 0.f);
                    f16x4 hb;
                    hb[0] = (_Float16)h[0]; hb[1] = (_Float16)h[1];
                    hb[2] = (_Float16)h[2]; hb[3] = (_Float16)h[3];
                    oacc[nt] = __builtin_amdgcn_mfma_f32_16x16x16f16(a2f, hb, oacc[nt], 0, 0, 0);
                }
            }
            if (quad < 2) {
                #pragma unroll
                for (int nt = 0; nt < 4; ++nt) {
                    float4 o4 = make_float4(oacc[nt][0], oacc[nt][1], oacc[nt][2], oacc[nt][3]);
                    *(float4*)(part + ((w * 64 + nt * 16 + i16) * 8 + quad * 4)) = o4;
                }
            }
        }
        __syncthreads();

        // reduce partials + residual + LN2
        if (t < 464) {
            int z = t >> 3, g = t & 7;
            float s = 0.f;
            #pragma unroll
            for (int ww = 0; ww < 16; ++ww) s += part[(ww * 64 + z) * 8 + g];
            float a = xs[t] + s + f2bs[li * 8 + g];
            float s8 = a + __shfl_xor(a, 1);
            s8 += __shfl_xor(s8, 2);
            s8 += __shfl_xor(s8, 4);
            float mu = s8 * 0.125f;
            float d = a - mu;
            float vv = d * d;
            vv += __shfl_xor(vv, 1); vv += __shfl_xor(vv, 2); vv += __shfl_xor(vv, 4);
            float inv = rsqrtf(vv * 0.125f + 1e-5f);
            xs[t] = d * inv * l2gs[li * 8 + g] + l2bs[li * 8 + g];
        }
        __syncthreads();
    }

    // ---------------- head ----------------
    {
        float* cat = part;               // [0..1017]
        float* partial = part + 4096;    // [16][64]
        const float* rg = rna + (size_t)b * RNAIN;
        for (int i = t; i < RNAIN; i += 1024) cat[i] = rg[i];
        __syncthreads();
        int j = lane;
        int k0 = w * 93;
        int k1 = (k0 + 93 < NCAT) ? (k0 + 93) : NCAT;
        float a = (w == 0) ? bprime[j] : 0.f;
        #pragma unroll 4
        for (int k = k0; k < k1; ++k) {
            float ck = (k < RNAIN) ? cat[k] : xs[k - RNAIN];
            a += ck * WcatT[k * 64 + j];
        }
        partial[w * 64 + j] = a;
        __syncthreads();
        if (t < 64) {
            float s = 0.f;
            #pragma unroll
            for (int ww = 0; ww < 16; ++ww) s += partial[ww * 64 + t];
            h1s[t] = s;
        }
    }
    __syncthreads();
    if (t < 8) {
        float a2 = c2_b[t];
        #pragma unroll 8
        for (int m = 0; m < 64; ++m) a2 += h1s[m] * c2_w[t * 64 + m];
        h2s[t] = a2;
    }
    __syncthreads();
    if (t == 0) {
        float a3 = c3_b[0];
        #pragma unroll
        for (int jj = 0; jj < 8; ++jj) a3 += h2s[jj] * c3_w[jj];
        out[b] = a3;
    }
}

extern "C" void kernel_launch(void* const* d_in, const int* in_sizes, int n_in,
                              void* d_out, int out_size, void* d_ws, size_t ws_size,
                              hipStream_t stream) {
    const float* rna    = (const float*)d_in[0];
    const float* drug   = (const float*)d_in[1];
    const float* lin1_w = (const float*)d_in[2];
    const float* lin1_b = (const float*)d_in[3];
    const float* lin2_w = (const float*)d_in[4];
    const float* lin2_b = (const float*)d_in[5];
    const float* chem_w = (const float*)d_in[6];
    const float* pos_w  = (const float*)d_in[7];
    const float* qkv_w  = (const float*)d_in[8];
    const float* qkv_b  = (const float*)d_in[9];
    const float* out_w  = (const float*)d_in[10];
    const float* out_b  = (const float*)d_in[11];
    const float* ln1_g  = (const float*)d_in[12];
    const float* ln1_b  = (const float*)d_in[13];
    const float* ff1_w  = (const float*)d_in[14];
    const float* ff1_b  = (const float*)d_in[15];
    const float* ff2_w  = (const float*)d_in[16];
    const float* ff2_b  = (const float*)d_in[17];
    const float* ln2_g  = (const float*)d_in[18];
    const float* ln2_b  = (const float*)d_in[19];
    const float* c1_w   = (const float*)d_in[20];
    const float* c1_b   = (const float*)d_in[21];
    const float* c2_w   = (const float*)d_in[22];
    const float* c2_b   = (const float*)d_in[23];
    const float* c3_w   = (const float*)d_in[24];
    const float* c3_b   = (const float*)d_in[25];
    float* ws  = (float*)d_ws;
    float* out = (float*)d_out;

    hipLaunchKernelGGL(prep_kernel, dim3(17), dim3(1024), 0, stream,
                       lin1_w, lin1_b, lin2_w, lin2_b, c1_w, c1_b, ws);
    hipLaunchKernelGGL(mega_kernel, dim3(BB), dim3(1024), 0, stream,
                       drug, chem_w, pos_w, ff1_w, ff2_w, ff1_b,
                       qkv_w, qkv_b, out_w, out_b,
                       ln1_g, ln1_b, ff2_b, ln2_g, ln2_b,
                       rna, ws + OFF_WCATT, ws + OFF_BPRIME,
                       c2_w, c2_b, c3_w, c3_b, out);
}

// Round 2
// 698.879 us; speedup vs baseline: 1.0482x; 1.0482x over previous
//
#include <hip/hip_runtime.h>

#define BB 512
#define LDIM 2713
#define ZDIM 58
#define GDIM 8
#define NLAYER 6
#define FFDIM 2048
#define RNAIN 1018
#define CATDIM 528
#define NCAT 1482    // 1018 rna-folded + 464 flat
#define LQ 679       // ceil(2713/4)

typedef float v2f __attribute__((ext_vector_type(2)));
typedef float f32x4 __attribute__((ext_vector_type(4)));
typedef _Float16 f16x4 __attribute__((ext_vector_type(4)));

// ---------------- ws layout (floats) ----------------
#define OFF_WCATT  0            // WcatT [1482][64]   94848
#define OFF_BPRIME 94848        // bprime[64]

// ============ prep: WcatT + bprime, coalesced, ONE dispatch ============
// WcatT[k][j] = sum_m c1[j][m] * U[m][k],  U[m][k] = sum_n lin2[m][n]*lin1[n][k]
// blocks 0..15: one 64-wide k-tile each. block 16: bprime + flat-part copy.
__global__ __launch_bounds__(1024) void prep_kernel(
    const float* __restrict__ lin1_w, const float* __restrict__ lin1_b,
    const float* __restrict__ lin2_w, const float* __restrict__ lin2_b,
    const float* __restrict__ c1_w, const float* __restrict__ c1_b,
    float* __restrict__ ws) {
    __shared__ float lin1s[256 * 64];   // [n][kloc]
    __shared__ float Ut[64 * 64];       // [m][kloc]
    __shared__ float c1T[64 * 64];      // [m][j]
    const int t = threadIdx.x;
    float* WcatT = ws + OFF_WCATT;

    if (blockIdx.x == 16) {
        // bR partials: thread (m = t>>4, q = t&15) covers n in [q*16, q*16+16)
        {
            int m = t >> 4, q = t & 15;
            float a = 0.f;
            #pragma unroll
            for (int nn = 0; nn < 16; ++nn)
                a += lin2_w[m * 256 + q * 16 + nn] * lin1_b[q * 16 + nn];
            lin1s[m * 16 + q] = a;
        }
        __syncthreads();
        if (t < 64) {                    // bR[m]
            float a = lin2_b[t];
            #pragma unroll
            for (int q = 0; q < 16; ++q) a += lin1s[t * 16 + q];
            Ut[t] = a;
        }
        __syncthreads();
        if (t < 64) {                    // bprime[j] = c1_b + c1[:, :64] @ bR
            float a = c1_b[t];
            #pragma unroll 8
            for (int m = 0; m < 64; ++m) a += c1_w[t * CATDIM + m] * Ut[m];
            ws[OFF_BPRIME + t] = a;
        }
        // flat-part rows of WcatT (reads coalesced in kk; scattered writes ok)
        for (int i = t; i < 464 * 64; i += 1024) {
            int j = i / 464, kk = i % 464;
            WcatT[(RNAIN + kk) * 64 + j] = c1_w[j * CATDIM + 64 + kk];
        }
        return;
    }

    const int k0 = blockIdx.x * 64;
    const int nk = (RNAIN - k0 < 64) ? (RNAIN - k0) : 64;   // block 15: 58
    // stage lin1 k-slice: lin1s[n][kl] (coalesced read+write)
    for (int i = t; i < 256 * 64; i += 1024) {
        int n = i >> 6, kl = i & 63;
        lin1s[i] = (kl < nk) ? lin1_w[n * RNAIN + k0 + kl] : 0.f;
    }
    // stage c1 transposed: c1T[m][j] = c1_w[j][m] (coalesced read in m)
    for (int i = t; i < 64 * 64; i += 1024) {
        int j = i >> 6, m = i & 63;
        c1T[m * 64 + j] = c1_w[j * CATDIM + m];
    }
    __syncthreads();
    // U: m wave-uniform, kl = lane (lin2 broadcast, lin1s conflict-free)
    for (int mp = 0; mp < 4; ++mp) {
        int m = (t >> 6) + mp * 16;
        int kl = t & 63;
        const float* l2r = lin2_w + m * 256;
        float a = 0.f;
        #pragma unroll 8
        for (int n = 0; n < 256; ++n) a += l2r[n] * lin1s[n * 64 + kl];
        Ut[m * 64 + kl] = a;
    }
    __syncthreads();
    // WcatT tile: kr wave-uniform (Ut broadcast), j = lane (c1T + write coalesced)
    for (int kp = 0; kp < 4; ++kp) {
        int kr = (t >> 6) + kp * 16;
        int j = t & 63;
        if (kr < nk) {
            float a = 0.f;
            #pragma unroll 8
            for (int m = 0; m < 64; ++m) a += Ut[m * 64 + kr] * c1T[m * 64 + j];
            WcatT[(k0 + kr) * 64 + j] = a;
        }
    }
}

// ============ mega: embed (in-block) -> 6 layers -> head ============
// 512 threads (8 waves), 4 blocks/CU: layer phases ~91% lane-active.
__global__ __launch_bounds__(512, 8) void mega_kernel(
    const float* __restrict__ drug, const float* __restrict__ chem_w,
    const float* __restrict__ pos_w,
    const float* __restrict__ ff1_w, const float* __restrict__ ff2_w,
    const float* __restrict__ ff1_b,
    const float* __restrict__ qkv_w, const float* __restrict__ qkv_b,
    const float* __restrict__ out_w, const float* __restrict__ out_b,
    const float* __restrict__ ln1_g, const float* __restrict__ ln1_b,
    const float* __restrict__ ff2_b,
    const float* __restrict__ ln2_g, const float* __restrict__ ln2_b,
    const float* __restrict__ rna, const float* __restrict__ WcatT,
    const float* __restrict__ bprime,
    const float* __restrict__ c2_w, const float* __restrict__ c2_b,
    const float* __restrict__ c3_w, const float* __restrict__ c3_b,
    float* __restrict__ out) {
    __shared__ float smem[9152];
    // embed-phase aliases:
    float* cwl    = smem;           // 5432(+8) chem quarter [i][g]
    float* part_e = smem + 5440;    // 3712 = [w8][z58*8]
    // main-phase aliases:
    float* xs    = smem;            // 512
    float* qs    = smem + 512;      // 480  [h][60]
    float* ks    = smem + 992;      // 480
    float* vs    = smem + 1472;     // 480
    float* part  = smem + 1952;     // 4096 [w8][64][8]
    float* qkvws = smem + 6048;     // 1152
    float* qkvbs = smem + 7200;     // 144
    float* outws = smem + 7344;     // 384
    float* outbs = smem + 7728;     // 48
    float* l1gs  = smem + 7776;     // 48
    float* l1bs  = smem + 7824;     // 48
    float* l2gs  = smem + 7872;     // 48
    float* l2bs  = smem + 7920;     // 48
    float* f2bs  = smem + 7968;     // 48
    float* h1s   = smem + 8016;     // 64
    float* h2s   = smem + 8080;     // 8

    const int b = blockIdx.x;
    const int t = threadIdx.x;
    const int w = __builtin_amdgcn_readfirstlane(t >> 6);   // wave id 0..7
    const int lane = t & 63;
    const int quad = lane >> 4;
    const int i16 = lane & 15;

    // ---------------- embed ----------------
    {
        const int zc = (lane < ZDIM) ? lane : (ZDIM - 1);
        v2f acc0 = {0.f, 0.f}, acc1 = {0.f, 0.f}, acc2 = {0.f, 0.f}, acc3 = {0.f, 0.f};
        for (int q = 0; q < 4; ++q) {
            const int l0 = q * LQ;
            const int nrows = (LDIM - l0 < LQ) ? (LDIM - l0) : LQ;   // 679,679,679,676
            __syncthreads();
            #pragma unroll
            for (int g = 0; g < 8; ++g)
                for (int i = t; i < nrows; i += 512)
                    cwl[i * 8 + g] = chem_w[g * LDIM + l0 + i];
            __syncthreads();
            const float* dp = drug + (size_t)b * (LDIM * ZDIM) + (size_t)l0 * ZDIM;
            int r0 = w * 85;
            int r1 = (r0 + 85 < nrows) ? (r0 + 85) : nrows;
            int r = r0;
            for (; r + 4 <= r1; r += 4) {
                float d0 = dp[(r + 0) * ZDIM + zc];
                float d1 = dp[(r + 1) * ZDIM + zc];
                float d2 = dp[(r + 2) * ZDIM + zc];
                float d3 = dp[(r + 3) * ZDIM + zc];
                const v2f* c0 = (const v2f*)(cwl + (r + 0) * 8);
                const v2f* c1 = (const v2f*)(cwl + (r + 1) * 8);
                const v2f* c2 = (const v2f*)(cwl + (r + 2) * 8);
                const v2f* c3 = (const v2f*)(cwl + (r + 3) * 8);
                v2f dd;
                dd = (v2f){d0, d0};
                acc0 += c0[0] * dd; acc1 += c0[1] * dd; acc2 += c0[2] * dd; acc3 += c0[3] * dd;
                dd = (v2f){d1, d1};
                acc0 += c1[0] * dd; acc1 += c1[1] * dd; acc2 += c1[2] * dd; acc3 += c1[3] * dd;
                dd = (v2f){d2, d2};
                acc0 += c2[0] * dd; acc1 += c2[1] * dd; acc2 += c2[2] * dd; acc3 += c2[3] * dd;
                dd = (v2f){d3, d3};
                acc0 += c3[0] * dd; acc1 += c3[1] * dd; acc2 += c3[2] * dd; acc3 += c3[3] * dd;
            }
            for (; r < r1; ++r) {
                float d = dp[r * ZDIM + zc];
                const v2f* cc = (const v2f*)(cwl + r * 8);
                v2f dd = {d, d};
                acc0 += cc[0] * dd; acc1 += cc[1] * dd; acc2 += cc[2] * dd; acc3 += cc[3] * dd;
            }
        }
        if (lane < ZDIM) {
            v2f* pr = (v2f*)(part_e + w * 464 + zc * 8);
            pr[0] = acc0; pr[1] = acc1; pr[2] = acc2; pr[3] = acc3;
        }
        __syncthreads();
        if (t < 464) {
            int z = t >> 3, g = t & 7;
            float s = pos_w[g * ZDIM + z];
            #pragma unroll
            for (int ww = 0; ww < 8; ++ww) s += part_e[ww * 464 + t];
            xs[t] = s;                 // xs overlaps cwl (dead)
        } else if (t < 512) {
            xs[t] = 0.f;               // zero pad rows z=58..63
        }
        __syncthreads();               // part_e dead after this
    }

    // ---- hoist small per-layer weights (overwrites dead part_e region) ----
    for (int i = t; i < 1152; i += 512) qkvws[i] = qkv_w[i];
    if (t < 144) qkvbs[t] = qkv_b[t];
    if (t < 384) outws[t] = out_w[t];
    if (t < 48) {
        outbs[t] = out_b[t];
        l1gs[t] = ln1_g[t]; l1bs[t] = ln1_b[t];
        l2gs[t] = ln2_g[t]; l2bs[t] = ln2_b[t];
        f2bs[t] = ff2_b[t];
    }
    __syncthreads();

    // ---------------- 6 transformer layers (4 barriers each) ----------------
    for (int li = 0; li < NLAYER; ++li) {
        // qkv projection: thread = (z, h)
        if (t < 464) {
            int z = t >> 3, h = t & 7;
            const float4* xr = (const float4*)(xs + z * 8);
            float4 x0 = xr[0], x1 = xr[1];
            #pragma unroll
            for (int p = 0; p < 3; ++p) {
                int j = p * 8 + h;
                const float4* wr = (const float4*)(qkvws + li * 192 + j * 8);
                float4 w0 = wr[0], w1 = wr[1];
                float a = qkvbs[li * 24 + j]
                        + x0.x * w0.x + x0.y * w0.y + x0.z * w0.z + x0.w * w0.w
                        + x1.x * w1.x + x1.y * w1.y + x1.z * w1.z + x1.w * w1.w;
                float* dst = (p == 0) ? qs : (p == 1) ? ks : vs;
                dst[h * 60 + z] = a;
            }
        }
        __syncthreads();

        // attention + out-proj + residual + LN1, fused via 8-lane shuffles
        if (t < 464) {
            int h = t & 7, s = t >> 3;
            float q = qs[h * 60 + s];
            const float4* kr = (const float4*)(ks + h * 60);
            const float4* vr = (const float4*)(vs + h * 60);
            float sum = 0.f, oa = 0.f;
            #pragma unroll 2
            for (int c = 0; c < 14; ++c) {
                float4 k4 = kr[c], v4 = vr[c];
                float e0 = __expf(q * k4.x); sum += e0; oa += e0 * v4.x;
                float e1 = __expf(q * k4.y); sum += e1; oa += e1 * v4.y;
                float e2 = __expf(q * k4.z); sum += e2; oa += e2 * v4.z;
                float e3 = __expf(q * k4.w); sum += e3; oa += e3 * v4.w;
            }
            {
                const float* kk = ks + h * 60;
                const float* vv = vs + h * 60;
                float e0 = __expf(q * kk[56]); sum += e0; oa += e0 * vv[56];
                float e1 = __expf(q * kk[57]); sum += e1; oa += e1 * vv[57];
            }
            float o = oa / sum;                 // attn output for (z=s, head=h)
            // out-proj for (z=s, g=h): gather the 8 heads of this row via shfl
            int g = h;
            float a = outbs[li * 8 + g] + xs[t];
            const float* wr8 = outws + li * 64 + g * 8;
            #pragma unroll
            for (int hh = 0; hh < 8; ++hh)
                a += __shfl(o, hh, 8) * wr8[hh];
            float s8 = a + __shfl_xor(a, 1);
            s8 += __shfl_xor(s8, 2);
            s8 += __shfl_xor(s8, 4);
            float mu = s8 * 0.125f;
            float d = a - mu;
            float vv = d * d;
            vv += __shfl_xor(vv, 1); vv += __shfl_xor(vv, 2); vv += __shfl_xor(vv, 4);
            float inv = rsqrtf(vv * 0.125f + 1e-5f);
            xs[t] = d * inv * l1gs[li * 8 + g] + l1bs[li * 8 + g];
        }
        __syncthreads();

        // ---- FFN via MFMA f16: wave w owns f-slice [w*256, (w+1)*256) ----
        {
            f16x4 xb[4];
            #pragma unroll
            for (int nt = 0; nt < 4; ++nt) {
                if (quad < 2) {
                    const float4* xp = (const float4*)(xs + (nt * 16 + i16) * 8 + quad * 4);
                    float4 xv = *xp;
                    xb[nt][0] = (_Float16)xv.x; xb[nt][1] = (_Float16)xv.y;
                    xb[nt][2] = (_Float16)xv.z; xb[nt][3] = (_Float16)xv.w;
                } else {
                    xb[nt][0] = (_Float16)0.f; xb[nt][1] = (_Float16)0.f;
                    xb[nt][2] = (_Float16)0.f; xb[nt][3] = (_Float16)0.f;
                }
            }
            f32x4 oacc[4];
            #pragma unroll
            for (int nt = 0; nt < 4; ++nt) { oacc[nt][0]=0.f; oacc[nt][1]=0.f; oacc[nt][2]=0.f; oacc[nt][3]=0.f; }

            const float* w1p = ff1_w + ((size_t)li * FFDIM + w * 256) * 8;   // A[m=f][k=g]
            const float* a2p = ff2_w + (size_t)li * GDIM * FFDIM + w * 256;  // A[m=g][k=f]
            const float* b1p = ff1_b + li * FFDIM + w * 256;

            #pragma unroll 2
            for (int ft = 0; ft < 16; ++ft) {
                f16x4 w1f = {};
                if (lane < 32) {
                    f32x4 v = *(const f32x4*)(w1p + (size_t)(ft * 16 + i16) * 8 + quad * 4);
                    w1f[0] = (_Float16)v[0]; w1f[1] = (_Float16)v[1];
                    w1f[2] = (_Float16)v[2]; w1f[3] = (_Float16)v[3];
                }
                f16x4 a2f = {};
                if (i16 < 8) {
                    f32x4 v = *(const f32x4*)(a2p + (size_t)i16 * FFDIM + ft * 16 + quad * 4);
                    a2f[0] = (_Float16)v[0]; a2f[1] = (_Float16)v[1];
                    a2f[2] = (_Float16)v[2]; a2f[3] = (_Float16)v[3];
                }
                f32x4 b1v = *(const f32x4*)(b1p + ft * 16 + quad * 4);
                #pragma unroll
                for (int nt = 0; nt < 4; ++nt) {
                    f32x4 h = b1v;
                    h = __builtin_amdgcn_mfma_f32_16x16x16f16(w1f, xb[nt], h, 0, 0, 0);
                    h[0] = fmaxf(h[0], 0.f); h[1] = fmaxf(h[1], 0.f);
                    h[2] = fmaxf(h[2], 0.f); h[3] = fmaxf(h[3], 0.f);
                    f16x4 hb;
                    hb[0] = (_Float16)h[0]; hb[1] = (_Float16)h[1];
                    hb[2] = (_Float16)h[2]; hb[3] = (_Float16)h[3];
                    oacc[nt] = __builtin_amdgcn_mfma_f32_16x16x16f16(a2f, hb, oacc[nt], 0, 0, 0);
                }
            }
            if (quad < 2) {
                #pragma unroll
                for (int nt = 0; nt < 4; ++nt) {
                    float4 o4 = make_float4(oacc[nt][0], oacc[nt][1], oacc[nt][2], oacc[nt][3]);
                    *(float4*)(part + ((w * 64 + nt * 16 + i16) * 8 + quad * 4)) = o4;
                }
            }
        }
        __syncthreads();

        // reduce partials + residual + LN2
        if (t < 464) {
            int z = t >> 3, g = t & 7;
            float s = 0.f;
            #pragma unroll
            for (int ww = 0; ww < 8; ++ww) s += part[(ww * 64 + z) * 8 + g];
            float a = xs[t] + s + f2bs[li * 8 + g];
            float s8 = a + __shfl_xor(a, 1);
            s8 += __shfl_xor(s8, 2);
            s8 += __shfl_xor(s8, 4);
            float mu = s8 * 0.125f;
            float d = a - mu;
            float vv = d * d;
            vv += __shfl_xor(vv, 1); vv += __shfl_xor(vv, 2); vv += __shfl_xor(vv, 4);
            float inv = rsqrtf(vv * 0.125f + 1e-5f);
            xs[t] = d * inv * l2gs[li * 8 + g] + l2bs[li * 8 + g];
        }
        __syncthreads();
    }

    // ---------------- head ----------------
    {
        float* cat = part;               // [0..1017]
        float* partial = part + 1024;    // [8][64]
        const float* rg = rna + (size_t)b * RNAIN;
        for (int i = t; i < RNAIN; i += 512) cat[i] = rg[i];
        __syncthreads();
        int j = lane;
        int k0 = w * 186;
        int k1 = (k0 + 186 < NCAT) ? (k0 + 186) : NCAT;
        float a = (w == 0) ? bprime[j] : 0.f;
        #pragma unroll 4
        for (int k = k0; k < k1; ++k) {
            float ck = (k < RNAIN) ? cat[k] : xs[k - RNAIN];
            a += ck * WcatT[k * 64 + j];
        }
        partial[w * 64 + j] = a;
        __syncthreads();
        if (t < 64) {
            float s = 0.f;
            #pragma unroll
            for (int ww = 0; ww < 8; ++ww) s += partial[ww * 64 + t];
            h1s[t] = s;
        }
    }
    __syncthreads();
    if (t < 8) {
        float a2 = c2_b[t];
        #pragma unroll 8
        for (int m = 0; m < 64; ++m) a2 += h1s[m] * c2_w[t * 64 + m];
        h2s[t] = a2;
    }
    __syncthreads();
    if (t == 0) {
        float a3 = c3_b[0];
        #pragma unroll
        for (int jj = 0; jj < 8; ++jj) a3 += h2s[jj] * c3_w[jj];
        out[b] = a3;
    }
}

extern "C" void kernel_launch(void* const* d_in, const int* in_sizes, int n_in,
                              void* d_out, int out_size, void* d_ws, size_t ws_size,
                              hipStream_t stream) {
    const float* rna    = (const float*)d_in[0];
    const float* drug   = (const float*)d_in[1];
    const float* lin1_w = (const float*)d_in[2];
    const float* lin1_b = (const float*)d_in[3];
    const float* lin2_w = (const float*)d_in[4];
    const float* lin2_b = (const float*)d_in[5];
    const float* chem_w = (const float*)d_in[6];
    const float* pos_w  = (const float*)d_in[7];
    const float* qkv_w  = (const float*)d_in[8];
    const float* qkv_b  = (const float*)d_in[9];
    const float* out_w  = (const float*)d_in[10];
    const float* out_b  = (const float*)d_in[11];
    const float* ln1_g  = (const float*)d_in[12];
    const float* ln1_b  = (const float*)d_in[13];
    const float* ff1_w  = (const float*)d_in[14];
    const float* ff1_b  = (const float*)d_in[15];
    const float* ff2_w  = (const float*)d_in[16];
    const float* ff2_b  = (const float*)d_in[17];
    const float* ln2_g  = (const float*)d_in[18];
    const float* ln2_b  = (const float*)d_in[19];
    const float* c1_w   = (const float*)d_in[20];
    const float* c1_b   = (const float*)d_in[21];
    const float* c2_w   = (const float*)d_in[22];
    const float* c2_b   = (const float*)d_in[23];
    const float* c3_w   = (const float*)d_in[24];
    const float* c3_b   = (const float*)d_in[25];
    float* ws  = (float*)d_ws;
    float* out = (float*)d_out;

    hipLaunchKernelGGL(prep_kernel, dim3(17), dim3(1024), 0, stream,
                       lin1_w, lin1_b, lin2_w, lin2_b, c1_w, c1_b, ws);
    hipLaunchKernelGGL(mega_kernel, dim3(BB), dim3(512), 0, stream,
                       drug, chem_w, pos_w, ff1_w, ff2_w, ff1_b,
                       qkv_w, qkv_b, out_w, out_b,
                       ln1_g, ln1_b, ff2_b, ln2_g, ln2_b,
                       rna, ws + OFF_WCATT, ws + OFF_BPRIME,
                       c2_w, c2_b, c3_w, c3_b, out);
}

// Round 4
// 650.716 us; speedup vs baseline: 1.1258x; 1.0740x over previous
//
#include <hip/hip_runtime.h>

#define BB 512
#define LDIM 2713
#define ZDIM 58
#define GDIM 8
#define NLAYER 6
#define FFDIM 2048
#define RNAIN 1018
#define CATDIM 528
#define NCAT 1482    // 1018 rna-folded + 464 flat
#define LQ 679       // ceil(2713/4)

typedef float v2f __attribute__((ext_vector_type(2)));
typedef float f32x4 __attribute__((ext_vector_type(4)));
typedef _Float16 f16x4 __attribute__((ext_vector_type(4)));

// ---------------- ws layout (floats) ----------------
#define OFF_WCATT  0            // WcatT [1482][64]        94848
#define OFF_BPRIME 94848        // bprime[64]              64
#define OFF_W1H    94912        // W1 A-frags f16 [6][128][32][4] = 98304 h (49152 f)
#define OFF_A2H    144064       // W2 A-frags f16 (49152 f)

// ============ prep: WcatT + bprime + f16 frag packs, ONE dispatch ============
// blocks 0..15: WcatT k-tile. block 16: bprime + flat copy. blocks 17..64: frag packs.
__global__ __launch_bounds__(1024) void prep_kernel(
    const float* __restrict__ lin1_w, const float* __restrict__ lin1_b,
    const float* __restrict__ lin2_w, const float* __restrict__ lin2_b,
    const float* __restrict__ c1_w, const float* __restrict__ c1_b,
    const float* __restrict__ ff1_w, const float* __restrict__ ff2_w,
    float* __restrict__ ws) {
    const int t = threadIdx.x;
    const int bx = blockIdx.x;
    float* WcatT = ws + OFF_WCATT;

    if (bx >= 17) {                      // ---- f16 MFMA fragment packing ----
        int tid = (bx - 17) * 1024 + t;  // 0..49151
        _Float16* w1hp = (_Float16*)(ws + OFF_W1H);
        _Float16* a2hp = (_Float16*)(ws + OFF_A2H);
        if (tid < NLAYER * 128 * 32) {   // W1 A-frag: A[m=f_local=i][k=g=q*4+j]
            int li = tid / 4096, rem = tid % 4096;
            int ft = rem >> 5, l32 = rem & 31;
            int q = l32 >> 4, i = l32 & 15;
            const float* src = ff1_w + ((size_t)li * FFDIM + ft * 16 + i) * 8 + q * 4;
            size_t dst = ((size_t)(li * 128 + ft) * 32 + l32) * 4;
            #pragma unroll
            for (int j = 0; j < 4; ++j) w1hp[dst + j] = (_Float16)src[j];
        } else {                          // W2 A-frag: A[m=g=i2][k=f=ft*16+q*4+j]
            int r2 = tid - NLAYER * 128 * 32;
            int li = r2 / 4096, rem = r2 % 4096;
            int ft = rem >> 5, s = rem & 31;
            int q = s >> 3, i2 = s & 7;
            const float* src = ff2_w + ((size_t)li * GDIM + i2) * FFDIM + ft * 16 + q * 4;
            size_t dst = ((size_t)(li * 128 + ft) * 32 + s) * 4;
            #pragma unroll
            for (int j = 0; j < 4; ++j) a2hp[dst + j] = (_Float16)src[j];
        }
        return;
    }

    __shared__ float lin1s[256 * 64];   // [n][kloc]
    __shared__ float Ut[64 * 64];       // [m][kloc]
    __shared__ float c1T[64 * 64];      // [m][j]

    if (bx == 16) {
        {   // bR partials: thread (m=t>>4, q=t&15) covers n in [q*16, q*16+16)
            int m = t >> 4, q = t & 15;
            float a = 0.f;
            #pragma unroll
            for (int nn = 0; nn < 16; ++nn)
                a += lin2_w[m * 256 + q * 16 + nn] * lin1_b[q * 16 + nn];
            lin1s[m * 16 + q] = a;
        }
        __syncthreads();
        if (t < 64) {                    // bR[m]
            float a = lin2_b[t];
            #pragma unroll
            for (int q = 0; q < 16; ++q) a += lin1s[t * 16 + q];
            Ut[t] = a;
        }
        __syncthreads();
        if (t < 64) {                    // bprime[j] = c1_b + c1[:, :64] @ bR
            float a = c1_b[t];
            #pragma unroll 8
            for (int m = 0; m < 64; ++m) a += c1_w[t * CATDIM + m] * Ut[m];
            ws[OFF_BPRIME + t] = a;
        }
        for (int i = t; i < 464 * 64; i += 1024) {   // flat-part rows of WcatT
            int j = i / 464, kk = i % 464;
            WcatT[(RNAIN + kk) * 64 + j] = c1_w[j * CATDIM + 64 + kk];
        }
        return;
    }

    // ---- k-tile blocks: WcatT[k][j] = sum_m c1[j][m] * U[m][k] ----
    const int k0 = bx * 64;
    const int nk = (RNAIN - k0 < 64) ? (RNAIN - k0) : 64;   // block 15: 58
    for (int i = t; i < 256 * 64; i += 1024) {
        int n = i >> 6, kl = i & 63;
        lin1s[i] = (kl < nk) ? lin1_w[n * RNAIN + k0 + kl] : 0.f;
    }
    for (int i = t; i < 64 * 64; i += 1024) {
        int j = i >> 6, m = i & 63;
        c1T[m * 64 + j] = c1_w[j * CATDIM + m];
    }
    __syncthreads();
    {   // U[m][kl]: n-outer, 1 LDS read serves 4 m's; lin2 loads are scalar-uniform
        const int kl = t & 63;
        const int mw = __builtin_amdgcn_readfirstlane(t >> 6);
        float a0 = 0.f, a1 = 0.f, a2 = 0.f, a3 = 0.f;
        for (int n = 0; n < 256; ++n) {
            float ls = lin1s[n * 64 + kl];
            a0 += lin2_w[(mw +  0) * 256 + n] * ls;
            a1 += lin2_w[(mw + 16) * 256 + n] * ls;
            a2 += lin2_w[(mw + 32) * 256 + n] * ls;
            a3 += lin2_w[(mw + 48) * 256 + n] * ls;
        }
        Ut[(mw +  0) * 64 + kl] = a0;
        Ut[(mw + 16) * 64 + kl] = a1;
        Ut[(mw + 32) * 64 + kl] = a2;
        Ut[(mw + 48) * 64 + kl] = a3;
    }
    __syncthreads();
    {   // WcatT tile: m-outer, c1T per-lane read serves 4 kr's; Ut reads broadcast
        const int j = t & 63;
        const int kw = __builtin_amdgcn_readfirstlane(t >> 6);
        float a0 = 0.f, a1 = 0.f, a2 = 0.f, a3 = 0.f;
        for (int m = 0; m < 64; ++m) {
            float cv = c1T[m * 64 + j];
            a0 += Ut[m * 64 + kw +  0] * cv;
            a1 += Ut[m * 64 + kw + 16] * cv;
            a2 += Ut[m * 64 + kw + 32] * cv;
            a3 += Ut[m * 64 + kw + 48] * cv;
        }
        if (kw +  0 < nk) WcatT[(k0 + kw +  0) * 64 + j] = a0;
        if (kw + 16 < nk) WcatT[(k0 + kw + 16) * 64 + j] = a1;
        if (kw + 32 < nk) WcatT[(k0 + kw + 32) * 64 + j] = a2;
        if (kw + 48 < nk) WcatT[(k0 + kw + 48) * 64 + j] = a3;
    }
}

// ============ mega: embed (in-block) -> 6 layers -> head ============
// 1024 threads (16 waves), 2 blocks/CU -> ~90% occupancy.
__global__ __launch_bounds__(1024, 8) void mega_kernel(
    const float* __restrict__ drug, const float* __restrict__ chem_w,
    const float* __restrict__ pos_w,
    const _Float16* __restrict__ w1h, const _Float16* __restrict__ a2h,
    const float* __restrict__ ff1_b,
    const float* __restrict__ qkv_w, const float* __restrict__ qkv_b,
    const float* __restrict__ out_w, const float* __restrict__ out_b,
    const float* __restrict__ ln1_g, const float* __restrict__ ln1_b,
    const float* __restrict__ ff2_b,
    const float* __restrict__ ln2_g, const float* __restrict__ ln2_b,
    const float* __restrict__ rna, const float* __restrict__ WcatT,
    const float* __restrict__ bprime,
    const float* __restrict__ c2_w, const float* __restrict__ c2_b,
    const float* __restrict__ c3_w, const float* __restrict__ c3_b,
    float* __restrict__ out) {
    __shared__ float smem[12864];
    // embed-phase aliases:
    float* cwl    = smem;           // 5440 = v2f cwl_v2[gp4][680]
    float* part_e = smem + 5440;    // 7424 = [w16][464]
    // main-phase aliases:
    float* xs    = smem;                          // 512
    _Float16* xh = (_Float16*)(smem + 512);       // 512 halves (256 f)
    float* qs    = smem + 768;      // 480  [h][60]
    float* ks    = smem + 1248;     // 480
    float* vs    = smem + 1728;     // 480
    float* part  = smem + 2208;     // 8192 [w16][64][8]
    float* qkvws = smem + 10400;    // 1152
    float* qkvbs = smem + 11552;    // 144
    float* outws = smem + 11696;    // 384
    float* outbs = smem + 12080;    // 48
    float* l1gs  = smem + 12128;    // 48
    float* l1bs  = smem + 12176;    // 48
    float* l2gs  = smem + 12224;    // 48
    float* l2bs  = smem + 12272;    // 48
    float* f2bs  = smem + 12320;    // 48
    float* h1s   = smem + 12368;    // 64
    float* h2s   = smem + 12432;    // 8

    const int b = blockIdx.x;
    const int t = threadIdx.x;
    const int w = __builtin_amdgcn_readfirstlane(t >> 6);   // wave id 0..15
    const int lane = t & 63;
    const int quad = lane >> 4;
    const int i16 = lane & 15;

    // ---------------- embed ----------------
    {
        const int zc = (lane < ZDIM) ? lane : (ZDIM - 1);
        v2f acc0 = {0.f, 0.f}, acc1 = {0.f, 0.f}, acc2 = {0.f, 0.f}, acc3 = {0.f, 0.f};
        for (int q = 0; q < 4; ++q) {
            const int l0 = q * LQ;
            const int nrows = (LDIM - l0 < LQ) ? (LDIM - l0) : LQ;   // 679,679,679,676
            __syncthreads();
            // stage chem quarter as paired-transpose: cwl_v2[gp][i] = {chem[2gp][l0+i], chem[2gp+1][l0+i]}
            #pragma unroll
            for (int gp = 0; gp < 4; ++gp)
                for (int i = t; i < nrows; i += 1024) {
                    v2f cv = { chem_w[(2 * gp) * LDIM + l0 + i],
                               chem_w[(2 * gp + 1) * LDIM + l0 + i] };
                    *(v2f*)(cwl + 2 * (gp * 680 + i)) = cv;
                }
            __syncthreads();
            const float* dp = drug + (size_t)b * (LDIM * ZDIM) + (size_t)l0 * ZDIM + zc;
            int r0 = w * 43;
            int r1 = (r0 + 43 < nrows) ? (r0 + 43) : nrows;
            int r = r0;
            for (; r + 8 <= r1; r += 8) {
                float d0 = dp[(r + 0) * ZDIM];
                float d1 = dp[(r + 1) * ZDIM];
                float d2 = dp[(r + 2) * ZDIM];
                float d3 = dp[(r + 3) * ZDIM];
                float d4 = dp[(r + 4) * ZDIM];
                float d5 = dp[(r + 5) * ZDIM];
                float d6 = dp[(r + 6) * ZDIM];
                float d7 = dp[(r + 7) * ZDIM];
                #pragma unroll
                for (int j = 0; j < 8; ++j) {
                    float dj = (j == 0) ? d0 : (j == 1) ? d1 : (j == 2) ? d2 : (j == 3) ? d3
                             : (j == 4) ? d4 : (j == 5) ? d5 : (j == 6) ? d6 : d7;
                    v2f dd = {dj, dj};
                    int rr = r + j;
                    acc0 += *(const v2f*)(cwl + 2 * (0 * 680 + rr)) * dd;
                    acc1 += *(const v2f*)(cwl + 2 * (1 * 680 + rr)) * dd;
                    acc2 += *(const v2f*)(cwl + 2 * (2 * 680 + rr)) * dd;
                    acc3 += *(const v2f*)(cwl + 2 * (3 * 680 + rr)) * dd;
                }
            }
            for (; r < r1; ++r) {
                float d = dp[r * ZDIM];
                v2f dd = {d, d};
                acc0 += *(const v2f*)(cwl + 2 * (0 * 680 + r)) * dd;
                acc1 += *(const v2f*)(cwl + 2 * (1 * 680 + r)) * dd;
                acc2 += *(const v2f*)(cwl + 2 * (2 * 680 + r)) * dd;
                acc3 += *(const v2f*)(cwl + 2 * (3 * 680 + r)) * dd;
            }
        }
        if (lane < ZDIM) {
            v2f* pr = (v2f*)(part_e + w * 464 + zc * 8);
            pr[0] = acc0; pr[1] = acc1; pr[2] = acc2; pr[3] = acc3;
        }
        __syncthreads();
        if (t < 464) {
            int z = t >> 3, g = t & 7;
            float s = pos_w[g * ZDIM + z];
            #pragma unroll
            for (int ww = 0; ww < 16; ++ww) s += part_e[ww * 464 + t];
            xs[t] = s;                 // xs overlaps cwl (dead)
        } else if (t < 512) {
            xs[t] = 0.f;               // zero pad rows z=58..63
            xh[t] = (_Float16)0.f;     // f16 pad stays 0 for all layers
        }
        __syncthreads();               // part_e dead after this
    }

    // ---- hoist small per-layer weights (overwrites dead part_e region) ----
    for (int i = t; i < 1152; i += 1024) qkvws[i] = qkv_w[i];
    if (t < 144) qkvbs[t] = qkv_b[t];
    if (t < 384) outws[t] = out_w[t];
    if (t < 48) {
        outbs[t] = out_b[t];
        l1gs[t] = ln1_g[t]; l1bs[t] = ln1_b[t];
        l2gs[t] = ln2_g[t]; l2bs[t] = ln2_b[t];
        f2bs[t] = ff2_b[t];
    }
    __syncthreads();

    // ---------------- 6 transformer layers (4 barriers each) ----------------
    for (int li = 0; li < NLAYER; ++li) {
        // qkv projection: grid-stride over all 1392 outputs (z, j)
        for (int i = t; i < 1392; i += 1024) {
            int z = i / 24, j = i - z * 24;
            const float4* xr = (const float4*)(xs + z * 8);
            float4 x0 = xr[0], x1 = xr[1];
            const float4* wr = (const float4*)(qkvws + li * 192 + j * 8);
            float4 w0 = wr[0], w1 = wr[1];
            float a = qkvbs[li * 24 + j]
                    + x0.x * w0.x + x0.y * w0.y + x0.z * w0.z + x0.w * w0.w
                    + x1.x * w1.x + x1.y * w1.y + x1.z * w1.z + x1.w * w1.w;
            int p = j >> 3, h = j & 7;
            float* dst = (p == 0) ? qs : (p == 1) ? ks : vs;
            dst[h * 60 + z] = a;
        }
        __syncthreads();

        // attention + out-proj + residual + LN1 (fused via 8-lane shuffles)
        if (t < 464) {
            int h = t & 7, s = t >> 3;
            float q = qs[h * 60 + s];
            const float4* kr = (const float4*)(ks + h * 60);
            const float4* vr = (const float4*)(vs + h * 60);
            float sum = 0.f, oa = 0.f;
            #pragma unroll 2
            for (int c = 0; c < 14; ++c) {
                float4 k4 = kr[c], v4 = vr[c];
                float e0 = __expf(q * k4.x); sum += e0; oa += e0 * v4.x;
                float e1 = __expf(q * k4.y); sum += e1; oa += e1 * v4.y;
                float e2 = __expf(q * k4.z); sum += e2; oa += e2 * v4.z;
                float e3 = __expf(q * k4.w); sum += e3; oa += e3 * v4.w;
            }
            {
                const float* kk = ks + h * 60;
                const float* vv = vs + h * 60;
                float e0 = __expf(q * kk[56]); sum += e0; oa += e0 * vv[56];
                float e1 = __expf(q * kk[57]); sum += e1; oa += e1 * vv[57];
            }
            float o = oa / sum;                 // attn output for (z=s, head=h)
            int g = h;
            float a = outbs[li * 8 + g] + xs[t];
            const float* wr8 = outws + li * 64 + g * 8;
            #pragma unroll
            for (int hh = 0; hh < 8; ++hh)
                a += __shfl(o, hh, 8) * wr8[hh];
            float s8 = a + __shfl_xor(a, 1);
            s8 += __shfl_xor(s8, 2);
            s8 += __shfl_xor(s8, 4);
            float mu = s8 * 0.125f;
            float d = a - mu;
            float vv = d * d;
            vv += __shfl_xor(vv, 1); vv += __shfl_xor(vv, 2); vv += __shfl_xor(vv, 4);
            float inv = rsqrtf(vv * 0.125f + 1e-5f);
            float xn = d * inv * l1gs[li * 8 + g] + l1bs[li * 8 + g];
            xs[t] = xn;
            xh[t] = (_Float16)xn;     // packed f16 copy for the FFN MFMA
        }
        __syncthreads();

        // ---- FFN via MFMA f16: wave w owns f-slice [w*128, (w+1)*128) ----
        {
            f16x4 xb[4];
            #pragma unroll
            for (int nt = 0; nt < 4; ++nt) {
                if (quad < 2) {
                    xb[nt] = *(const f16x4*)(xh + (nt * 16 + i16) * 8 + quad * 4);
                } else {
                    xb[nt][0] = (_Float16)0.f; xb[nt][1] = (_Float16)0.f;
                    xb[nt][2] = (_Float16)0.f; xb[nt][3] = (_Float16)0.f;
                }
            }
            f32x4 oacc[4];
            #pragma unroll
            for (int nt = 0; nt < 4; ++nt) { oacc[nt][0]=0.f; oacc[nt][1]=0.f; oacc[nt][2]=0.f; oacc[nt][3]=0.f; }

            const _Float16* w1p = w1h + ((size_t)(li * 128 + w * 8) * 32) * 4;
            const _Float16* a2p = a2h + ((size_t)(li * 128 + w * 8) * 32) * 4;
            const float* b1p = ff1_b + li * FFDIM + w * 128;

            #pragma unroll
            for (int ft = 0; ft < 8; ++ft) {
                f16x4 w1f = {};
                if (lane < 32) w1f = *(const f16x4*)(w1p + (size_t)(ft * 32 + lane) * 4);
                f16x4 a2f = {};
                if (i16 < 8) a2f = *(const f16x4*)(a2p + (size_t)(ft * 32 + quad * 8 + i16) * 4);
                f32x4 b1v = *(const f32x4*)(b1p + ft * 16 + quad * 4);
                #pragma unroll
                for (int nt = 0; nt < 4; ++nt) {
                    f32x4 h = __builtin_amdgcn_mfma_f32_16x16x16f16(w1f, xb[nt], b1v, 0, 0, 0);
                    h[0] = fmaxf(h[0], 0.f); h[1] = fmaxf(h[1], 0.f);
                    h[2] = fmaxf(h[2], 0.f); h[3] = fmaxf(h[3], 0.f);
                    f16x4 hb;
                    hb[0] = (_Float16)h[0]; hb[1] = (_Float16)h[1];
                    hb[2] = (_Float16)h[2]; hb[3] = (_Float16)h[3];
                    oacc[nt] = __builtin_amdgcn_mfma_f32_16x16x16f16(a2f, hb, oacc[nt], 0, 0, 0);
                }
            }
            if (quad < 2) {
                #pragma unroll
                for (int nt = 0; nt < 4; ++nt) {
                    float4 o4 = make_float4(oacc[nt][0], oacc[nt][1], oacc[nt][2], oacc[nt][3]);
                    *(float4*)(part + ((w * 64 + nt * 16 + i16) * 8 + quad * 4)) = o4;
                }
            }
        }
        __syncthreads();

        // reduce partials + residual + LN2
        if (t < 464) {
            int z = t >> 3, g = t & 7;
            float s = 0.f;
            #pragma unroll
            for (int ww = 0; ww < 16; ++ww) s += part[(ww * 64 + z) * 8 + g];
            float a = xs[t] + s + f2bs[li * 8 + g];
            float s8 = a + __shfl_xor(a, 1);
            s8 += __shfl_xor(s8, 2);
            s8 += __shfl_xor(s8, 4);
            float mu = s8 * 0.125f;
            float d = a - mu;
            float vv = d * d;
            vv += __shfl_xor(vv, 1); vv += __shfl_xor(vv, 2); vv += __shfl_xor(vv, 4);
            float inv = rsqrtf(vv * 0.125f + 1e-5f);
            xs[t] = d * inv * l2gs[li * 8 + g] + l2bs[li * 8 + g];
        }
        __syncthreads();
    }

    // ---------------- head ----------------
    {
        float* cat = part;               // [0..1017]
        float* partial = part + 2048;    // [16][64]
        const float* rg = rna + (size_t)b * RNAIN;
        for (int i = t; i < RNAIN; i += 1024) cat[i] = rg[i];
        __syncthreads();
        int j = lane;
        int k0 = w * 93;
        int k1 = (k0 + 93 < NCAT) ? (k0 + 93) : NCAT;
        float a = (w == 0) ? bprime[j] : 0.f;
        #pragma unroll 4
        for (int k = k0; k < k1; ++k) {
            float ck = (k < RNAIN) ? cat[k] : xs[k - RNAIN];
            a += ck * WcatT[k * 64 + j];
        }
        partial[w * 64 + j] = a;
        __syncthreads();
        if (t < 64) {
            float s = 0.f;
            #pragma unroll
            for (int ww = 0; ww < 16; ++ww) s += partial[ww * 64 + t];
            h1s[t] = s;
        }
    }
    __syncthreads();
    if (t < 8) {
        float a2 = c2_b[t];
        #pragma unroll 8
        for (int m = 0; m < 64; ++m) a2 += h1s[m] * c2_w[t * 64 + m];
        h2s[t] = a2;
    }
    __syncthreads();
    if (t == 0) {
        float a3 = c3_b[0];
        #pragma unroll
        for (int jj = 0; jj < 8; ++jj) a3 += h2s[jj] * c3_w[jj];
        out[b] = a3;
    }
}

extern "C" void kernel_launch(void* const* d_in, const int* in_sizes, int n_in,
                              void* d_out, int out_size, void* d_ws, size_t ws_size,
                              hipStream_t stream) {
    const float* rna    = (const float*)d_in[0];
    const float* drug   = (const float*)d_in[1];
    const float* lin1_w = (const float*)d_in[2];
    const float* lin1_b = (const float*)d_in[3];
    const float* lin2_w = (const float*)d_in[4];
    const float* lin2_b = (const float*)d_in[5];
    const float* chem_w = (const float*)d_in[6];
    const float* pos_w  = (const float*)d_in[7];
    const float* qkv_w  = (const float*)d_in[8];
    const float* qkv_b  = (const float*)d_in[9];
    const float* out_w  = (const float*)d_in[10];
    const float* out_b  = (const float*)d_in[11];
    const float* ln1_g  = (const float*)d_in[12];
    const float* ln1_b  = (const float*)d_in[13];
    const float* ff1_w  = (const float*)d_in[14];
    const float* ff1_b  = (const float*)d_in[15];
    const float* ff2_w  = (const float*)d_in[16];
    const float* ff2_b  = (const float*)d_in[17];
    const float* ln2_g  = (const float*)d_in[18];
    const float* ln2_b  = (const float*)d_in[19];
    const float* c1_w   = (const float*)d_in[20];
    const float* c1_b   = (const float*)d_in[21];
    const float* c2_w   = (const float*)d_in[22];
    const float* c2_b   = (const float*)d_in[23];
    const float* c3_w   = (const float*)d_in[24];
    const float* c3_b   = (const float*)d_in[25];
    float* ws  = (float*)d_ws;
    float* out = (float*)d_out;

    hipLaunchKernelGGL(prep_kernel, dim3(65), dim3(1024), 0, stream,
                       lin1_w, lin1_b, lin2_w, lin2_b, c1_w, c1_b, ff1_w, ff2_w, ws);
    hipLaunchKernelGGL(mega_kernel, dim3(BB), dim3(1024), 0, stream,
                       drug, chem_w, pos_w,
                       (const _Float16*)(ws + OFF_W1H), (const _Float16*)(ws + OFF_A2H),
                       ff1_b, qkv_w, qkv_b, out_w, out_b,
                       ln1_g, ln1_b, ff2_b, ln2_g, ln2_b,
                       rna, ws + OFF_WCATT, ws + OFF_BPRIME,
                       c2_w, c2_b, c3_w, c3_b, out);
}

// Round 5
// 648.983 us; speedup vs baseline: 1.1288x; 1.0027x over previous
//
#include <hip/hip_runtime.h>

#define BB 512
#define LDIM 2713
#define ZDIM 58
#define GDIM 8
#define NLAYER 6
#define FFDIM 2048
#define RNAIN 1018
#define CATDIM 528
#define NCAT 1482    // 1018 rna-folded + 464 flat

typedef float v2f __attribute__((ext_vector_type(2)));
typedef float f32x4 __attribute__((ext_vector_type(4)));
typedef _Float16 f16x4 __attribute__((ext_vector_type(4)));

// ---------------- ws layout (floats) ----------------
#define OFF_WCATT  0            // WcatT [1482][64]        94848
#define OFF_BPRIME 94848        // bprime[64]              64
#define OFF_W1H    94912        // W1 A-frags f16 [6][128][32][4] = 98304 h (49152 f)
#define OFF_A2H    144064       // W2 A-frags f16 (49152 f)
#define OFF_CHEMT  193216       // chemT [2713][8]         21704 (32B-aligned rows)

// ============ prep: WcatT + bprime + f16 frag packs + chemT, ONE dispatch ============
// blocks 0..15: WcatT k-tile. block 16: bprime + flat copy. 17..64: frag packs. 65: chemT.
__global__ __launch_bounds__(1024) void prep_kernel(
    const float* __restrict__ lin1_w, const float* __restrict__ lin1_b,
    const float* __restrict__ lin2_w, const float* __restrict__ lin2_b,
    const float* __restrict__ c1_w, const float* __restrict__ c1_b,
    const float* __restrict__ ff1_w, const float* __restrict__ ff2_w,
    const float* __restrict__ chem_w,
    float* __restrict__ ws) {
    const int t = threadIdx.x;
    const int bx = blockIdx.x;
    float* WcatT = ws + OFF_WCATT;

    if (bx == 65) {                      // ---- chemT[l][g] = chem_w[g][l] ----
        float* chemT = ws + OFF_CHEMT;
        #pragma unroll
        for (int g = 0; g < 8; ++g)
            for (int l = t; l < LDIM; l += 1024)
                chemT[l * 8 + g] = chem_w[g * LDIM + l];
        return;
    }

    if (bx >= 17) {                      // ---- f16 MFMA fragment packing ----
        int tid = (bx - 17) * 1024 + t;  // 0..49151
        _Float16* w1hp = (_Float16*)(ws + OFF_W1H);
        _Float16* a2hp = (_Float16*)(ws + OFF_A2H);
        if (tid < NLAYER * 128 * 32) {   // W1 A-frag: A[m=f_local=i][k=g=q*4+j]
            int li = tid / 4096, rem = tid % 4096;
            int ft = rem >> 5, l32 = rem & 31;
            int q = l32 >> 4, i = l32 & 15;
            const float* src = ff1_w + ((size_t)li * FFDIM + ft * 16 + i) * 8 + q * 4;
            size_t dst = ((size_t)(li * 128 + ft) * 32 + l32) * 4;
            #pragma unroll
            for (int j = 0; j < 4; ++j) w1hp[dst + j] = (_Float16)src[j];
        } else {                          // W2 A-frag: A[m=g=i2][k=f=ft*16+q*4+j]
            int r2 = tid - NLAYER * 128 * 32;
            int li = r2 / 4096, rem = r2 % 4096;
            int ft = rem >> 5, s = rem & 31;
            int q = s >> 3, i2 = s & 7;
            const float* src = ff2_w + ((size_t)li * GDIM + i2) * FFDIM + ft * 16 + q * 4;
            size_t dst = ((size_t)(li * 128 + ft) * 32 + s) * 4;
            #pragma unroll
            for (int j = 0; j < 4; ++j) a2hp[dst + j] = (_Float16)src[j];
        }
        return;
    }

    __shared__ float lin1s[256 * 64];   // [n][kloc]
    __shared__ float Ut[64 * 64];       // [m][kloc]
    __shared__ float c1T[64 * 64];      // [m][j]

    if (bx == 16) {
        {   // bR partials: thread (m=t>>4, q=t&15) covers n in [q*16, q*16+16)
            int m = t >> 4, q = t & 15;
            float a = 0.f;
            #pragma unroll
            for (int nn = 0; nn < 16; ++nn)
                a += lin2_w[m * 256 + q * 16 + nn] * lin1_b[q * 16 + nn];
            lin1s[m * 16 + q] = a;
        }
        __syncthreads();
        if (t < 64) {                    // bR[m]
            float a = lin2_b[t];
            #pragma unroll
            for (int q = 0; q < 16; ++q) a += lin1s[t * 16 + q];
            Ut[t] = a;
        }
        __syncthreads();
        if (t < 64) {                    // bprime[j] = c1_b + c1[:, :64] @ bR
            float a = c1_b[t];
            #pragma unroll 8
            for (int m = 0; m < 64; ++m) a += c1_w[t * CATDIM + m] * Ut[m];
            ws[OFF_BPRIME + t] = a;
        }
        for (int i = t; i < 464 * 64; i += 1024) {   // flat-part rows of WcatT
            int j = i / 464, kk = i % 464;
            WcatT[(RNAIN + kk) * 64 + j] = c1_w[j * CATDIM + 64 + kk];
        }
        return;
    }

    // ---- k-tile blocks: WcatT[k][j] = sum_m c1[j][m] * U[m][k] ----
    const int k0 = bx * 64;
    const int nk = (RNAIN - k0 < 64) ? (RNAIN - k0) : 64;   // block 15: 58
    for (int i = t; i < 256 * 64; i += 1024) {
        int n = i >> 6, kl = i & 63;
        lin1s[i] = (kl < nk) ? lin1_w[n * RNAIN + k0 + kl] : 0.f;
    }
    for (int i = t; i < 64 * 64; i += 1024) {
        int j = i >> 6, m = i & 63;
        c1T[m * 64 + j] = c1_w[j * CATDIM + m];
    }
    __syncthreads();
    {   // U[m][kl]: n-outer, 1 LDS read serves 4 m's; lin2 loads are scalar-uniform
        const int kl = t & 63;
        const int mw = __builtin_amdgcn_readfirstlane(t >> 6);
        float a0 = 0.f, a1 = 0.f, a2 = 0.f, a3 = 0.f;
        for (int n = 0; n < 256; ++n) {
            float ls = lin1s[n * 64 + kl];
            a0 += lin2_w[(mw +  0) * 256 + n] * ls;
            a1 += lin2_w[(mw + 16) * 256 + n] * ls;
            a2 += lin2_w[(mw + 32) * 256 + n] * ls;
            a3 += lin2_w[(mw + 48) * 256 + n] * ls;
        }
        Ut[(mw +  0) * 64 + kl] = a0;
        Ut[(mw + 16) * 64 + kl] = a1;
        Ut[(mw + 32) * 64 + kl] = a2;
        Ut[(mw + 48) * 64 + kl] = a3;
    }
    __syncthreads();
    {   // WcatT tile: m-outer, c1T per-lane read serves 4 kr's; Ut reads broadcast
        const int j = t & 63;
        const int kw = __builtin_amdgcn_readfirstlane(t >> 6);
        float a0 = 0.f, a1 = 0.f, a2 = 0.f, a3 = 0.f;
        for (int m = 0; m < 64; ++m) {
            float cv = c1T[m * 64 + j];
            a0 += Ut[m * 64 + kw +  0] * cv;
            a1 += Ut[m * 64 + kw + 16] * cv;
            a2 += Ut[m * 64 + kw + 32] * cv;
            a3 += Ut[m * 64 + kw + 48] * cv;
        }
        if (kw +  0 < nk) WcatT[(k0 + kw +  0) * 64 + j] = a0;
        if (kw + 16 < nk) WcatT[(k0 + kw + 16) * 64 + j] = a1;
        if (kw + 32 < nk) WcatT[(k0 + kw + 32) * 64 + j] = a2;
        if (kw + 48 < nk) WcatT[(k0 + kw + 48) * 64 + j] = a3;
    }
}

// ============ mega: embed (SGPR-chem, no LDS) -> 6 layers -> head ============
// 1024 threads (16 waves), 2 blocks/CU.
__global__ __launch_bounds__(1024, 8) void mega_kernel(
    const float* __restrict__ drug, const float* __restrict__ chemT,
    const float* __restrict__ pos_w,
    const _Float16* __restrict__ w1h, const _Float16* __restrict__ a2h,
    const float* __restrict__ ff1_b,
    const float* __restrict__ qkv_w, const float* __restrict__ qkv_b,
    const float* __restrict__ out_w, const float* __restrict__ out_b,
    const float* __restrict__ ln1_g, const float* __restrict__ ln1_b,
    const float* __restrict__ ff2_b,
    const float* __restrict__ ln2_g, const float* __restrict__ ln2_b,
    const float* __restrict__ rna, const float* __restrict__ WcatT,
    const float* __restrict__ bprime,
    const float* __restrict__ c2_w, const float* __restrict__ c2_b,
    const float* __restrict__ c3_w, const float* __restrict__ c3_b,
    float* __restrict__ out) {
    __shared__ float smem[12864];
    // embed-phase alias (no LDS staging needed for chem anymore):
    float* part_e = smem + 5440;    // 7424 = [w16][464]
    // main-phase aliases:
    float* xs    = smem;                          // 512
    _Float16* xh = (_Float16*)(smem + 512);       // 512 halves (256 f)
    float* qs    = smem + 768;      // 480  [h][60]
    float* ks    = smem + 1248;     // 480
    float* vs    = smem + 1728;     // 480
    float* part  = smem + 2208;     // 8192 [w16][64][8]
    float* qkvws = smem + 10400;    // 1152
    float* qkvbs = smem + 11552;    // 144
    float* outws = smem + 11696;    // 384
    float* outbs = smem + 12080;    // 48
    float* l1gs  = smem + 12128;    // 48
    float* l1bs  = smem + 12176;    // 48
    float* l2gs  = smem + 12224;    // 48
    float* l2bs  = smem + 12272;    // 48
    float* f2bs  = smem + 12320;    // 48
    float* h1s   = smem + 12368;    // 64
    float* h2s   = smem + 12432;    // 8

    const int b = blockIdx.x;
    const int t = threadIdx.x;
    const int w = __builtin_amdgcn_readfirstlane(t >> 6);   // wave id 0..15
    const int lane = t & 63;
    const int quad = lane >> 4;
    const int i16 = lane & 15;

    // ---------------- embed: chem rows via uniform (scalar) loads ----------------
    {
        const int zc = (lane < ZDIM) ? lane : (ZDIM - 1);
        const float* dp = drug + (size_t)b * (LDIM * ZDIM) + zc;
        int r0 = w * 170;
        int r1 = (r0 + 170 < LDIM) ? (r0 + 170) : LDIM;   // wave 15: 163 rows
        f32x4 accA = {0.f, 0.f, 0.f, 0.f}, accB = {0.f, 0.f, 0.f, 0.f};
        int r = r0;
        for (; r + 4 <= r1; r += 4) {
            float d0 = dp[(size_t)(r + 0) * ZDIM];
            float d1 = dp[(size_t)(r + 1) * ZDIM];
            float d2 = dp[(size_t)(r + 2) * ZDIM];
            float d3 = dp[(size_t)(r + 3) * ZDIM];
            const f32x4* c0 = (const f32x4*)(chemT + (r + 0) * 8);
            const f32x4* c1 = (const f32x4*)(chemT + (r + 1) * 8);
            const f32x4* c2 = (const f32x4*)(chemT + (r + 2) * 8);
            const f32x4* c3 = (const f32x4*)(chemT + (r + 3) * 8);
            f32x4 dd;
            dd = (f32x4){d0, d0, d0, d0}; accA += c0[0] * dd; accB += c0[1] * dd;
            dd = (f32x4){d1, d1, d1, d1}; accA += c1[0] * dd; accB += c1[1] * dd;
            dd = (f32x4){d2, d2, d2, d2}; accA += c2[0] * dd; accB += c2[1] * dd;
            dd = (f32x4){d3, d3, d3, d3}; accA += c3[0] * dd; accB += c3[1] * dd;
        }
        for (; r < r1; ++r) {
            float d = dp[(size_t)r * ZDIM];
            const f32x4* cc = (const f32x4*)(chemT + r * 8);
            f32x4 dd = {d, d, d, d};
            accA += cc[0] * dd; accB += cc[1] * dd;
        }
        if (lane < ZDIM) {
            float4* pr = (float4*)(part_e + w * 464 + zc * 8);
            pr[0] = make_float4(accA[0], accA[1], accA[2], accA[3]);
            pr[1] = make_float4(accB[0], accB[1], accB[2], accB[3]);
        }
        __syncthreads();
        if (t < 464) {
            int z = t >> 3, g = t & 7;
            float s = pos_w[g * ZDIM + z];
            #pragma unroll
            for (int ww = 0; ww < 16; ++ww) s += part_e[ww * 464 + t];
            xs[t] = s;
        } else if (t < 512) {
            xs[t] = 0.f;               // zero pad rows z=58..63
            xh[t] = (_Float16)0.f;     // f16 pad stays 0 for all layers
        }
        __syncthreads();               // part_e dead after this
    }

    // ---- hoist small per-layer weights (overwrites dead part_e region) ----
    for (int i = t; i < 1152; i += 1024) qkvws[i] = qkv_w[i];
    if (t < 144) qkvbs[t] = qkv_b[t];
    if (t < 384) outws[t] = out_w[t];
    if (t < 48) {
        outbs[t] = out_b[t];
        l1gs[t] = ln1_g[t]; l1bs[t] = ln1_b[t];
        l2gs[t] = ln2_g[t]; l2bs[t] = ln2_b[t];
        f2bs[t] = ff2_b[t];
    }
    __syncthreads();

    // ---------------- 6 transformer layers (4 barriers each) ----------------
    for (int li = 0; li < NLAYER; ++li) {
        // qkv projection: grid-stride over all 1392 outputs (z, j)
        for (int i = t; i < 1392; i += 1024) {
            int z = i / 24, j = i - z * 24;
            const float4* xr = (const float4*)(xs + z * 8);
            float4 x0 = xr[0], x1 = xr[1];
            const float4* wr = (const float4*)(qkvws + li * 192 + j * 8);
            float4 w0 = wr[0], w1 = wr[1];
            float a = qkvbs[li * 24 + j]
                    + x0.x * w0.x + x0.y * w0.y + x0.z * w0.z + x0.w * w0.w
                    + x1.x * w1.x + x1.y * w1.y + x1.z * w1.z + x1.w * w1.w;
            int p = j >> 3, h = j & 7;
            float* dst = (p == 0) ? qs : (p == 1) ? ks : vs;
            dst[h * 60 + z] = a;
        }
        __syncthreads();

        // attention + out-proj + residual + LN1 (fused via 8-lane shuffles)
        if (t < 464) {
            int h = t & 7, s = t >> 3;
            float q = qs[h * 60 + s];
            const float4* kr = (const float4*)(ks + h * 60);
            const float4* vr = (const float4*)(vs + h * 60);
            float sum = 0.f, oa = 0.f;
            #pragma unroll 2
            for (int c = 0; c < 14; ++c) {
                float4 k4 = kr[c], v4 = vr[c];
                float e0 = __expf(q * k4.x); sum += e0; oa += e0 * v4.x;
                float e1 = __expf(q * k4.y); sum += e1; oa += e1 * v4.y;
                float e2 = __expf(q * k4.z); sum += e2; oa += e2 * v4.z;
                float e3 = __expf(q * k4.w); sum += e3; oa += e3 * v4.w;
            }
            {
                const float* kk = ks + h * 60;
                const float* vv = vs + h * 60;
                float e0 = __expf(q * kk[56]); sum += e0; oa += e0 * vv[56];
                float e1 = __expf(q * kk[57]); sum += e1; oa += e1 * vv[57];
            }
            float o = oa / sum;                 // attn output for (z=s, head=h)
            int g = h;
            float a = outbs[li * 8 + g] + xs[t];
            const float* wr8 = outws + li * 64 + g * 8;
            #pragma unroll
            for (int hh = 0; hh < 8; ++hh)
                a += __shfl(o, hh, 8) * wr8[hh];
            float s8 = a + __shfl_xor(a, 1);
            s8 += __shfl_xor(s8, 2);
            s8 += __shfl_xor(s8, 4);
            float mu = s8 * 0.125f;
            float d = a - mu;
            float vv = d * d;
            vv += __shfl_xor(vv, 1); vv += __shfl_xor(vv, 2); vv += __shfl_xor(vv, 4);
            float inv = rsqrtf(vv * 0.125f + 1e-5f);
            float xn = d * inv * l1gs[li * 8 + g] + l1bs[li * 8 + g];
            xs[t] = xn;
            xh[t] = (_Float16)xn;     // packed f16 copy for the FFN MFMA
        }
        __syncthreads();

        // ---- FFN via MFMA f16: wave w owns f-slice [w*128, (w+1)*128) ----
        {
            f16x4 xb[4];
            #pragma unroll
            for (int nt = 0; nt < 4; ++nt) {
                if (quad < 2) {
                    xb[nt] = *(const f16x4*)(xh + (nt * 16 + i16) * 8 + quad * 4);
                } else {
                    xb[nt][0] = (_Float16)0.f; xb[nt][1] = (_Float16)0.f;
                    xb[nt][2] = (_Float16)0.f; xb[nt][3] = (_Float16)0.f;
                }
            }
            f32x4 oacc[4];
            #pragma unroll
            for (int nt = 0; nt < 4; ++nt) { oacc[nt][0]=0.f; oacc[nt][1]=0.f; oacc[nt][2]=0.f; oacc[nt][3]=0.f; }

            const _Float16* w1p = w1h + ((size_t)(li * 128 + w * 8) * 32) * 4;
            const _Float16* a2p = a2h + ((size_t)(li * 128 + w * 8) * 32) * 4;
            const float* b1p = ff1_b + li * FFDIM + w * 128;

            #pragma unroll
            for (int ft = 0; ft < 8; ++ft) {
                f16x4 w1f = {};
                if (lane < 32) w1f = *(const f16x4*)(w1p + (size_t)(ft * 32 + lane) * 4);
                f16x4 a2f = {};
                if (i16 < 8) a2f = *(const f16x4*)(a2p + (size_t)(ft * 32 + quad * 8 + i16) * 4);
                f32x4 b1v = *(const f32x4*)(b1p + ft * 16 + quad * 4);
                #pragma unroll
                for (int nt = 0; nt < 4; ++nt) {
                    f32x4 h = __builtin_amdgcn_mfma_f32_16x16x16f16(w1f, xb[nt], b1v, 0, 0, 0);
                    h[0] = fmaxf(h[0], 0.f); h[1] = fmaxf(h[1], 0.f);
                    h[2] = fmaxf(h[2], 0.f); h[3] = fmaxf(h[3], 0.f);
                    f16x4 hb;
                    hb[0] = (_Float16)h[0]; hb[1] = (_Float16)h[1];
                    hb[2] = (_Float16)h[2]; hb[3] = (_Float16)h[3];
                    oacc[nt] = __builtin_amdgcn_mfma_f32_16x16x16f16(a2f, hb, oacc[nt], 0, 0, 0);
                }
            }
            if (quad < 2) {
                #pragma unroll
                for (int nt = 0; nt < 4; ++nt) {
                    float4 o4 = make_float4(oacc[nt][0], oacc[nt][1], oacc[nt][2], oacc[nt][3]);
                    *(float4*)(part + ((w * 64 + nt * 16 + i16) * 8 + quad * 4)) = o4;
                }
            }
        }
        __syncthreads();

        // reduce partials + residual + LN2
        if (t < 464) {
            int z = t >> 3, g = t & 7;
            float s = 0.f;
            #pragma unroll
            for (int ww = 0; ww < 16; ++ww) s += part[(ww * 64 + z) * 8 + g];
            float a = xs[t] + s + f2bs[li * 8 + g];
            float s8 = a + __shfl_xor(a, 1);
            s8 += __shfl_xor(s8, 2);
            s8 += __shfl_xor(s8, 4);
            float mu = s8 * 0.125f;
            float d = a - mu;
            float vv = d * d;
            vv += __shfl_xor(vv, 1); vv += __shfl_xor(vv, 2); vv += __shfl_xor(vv, 4);
            float inv = rsqrtf(vv * 0.125f + 1e-5f);
            xs[t] = d * inv * l2gs[li * 8 + g] + l2bs[li * 8 + g];
        }
        __syncthreads();
    }

    // ---------------- head ----------------
    {
        float* cat = part;               // [0..1017]
        float* partial = part + 2048;    // [16][64]
        const float* rg = rna + (size_t)b * RNAIN;
        for (int i = t; i < RNAIN; i += 1024) cat[i] = rg[i];
        __syncthreads();
        int j = lane;
        int k0 = w * 93;
        int k1 = (k0 + 93 < NCAT) ? (k0 + 93) : NCAT;
        float a = (w == 0) ? bprime[j] : 0.f;
        #pragma unroll 4
        for (int k = k0; k < k1; ++k) {
            float ck = (k < RNAIN) ? cat[k] : xs[k - RNAIN];
            a += ck * WcatT[k * 64 + j];
        }
        partial[w * 64 + j] = a;
        __syncthreads();
        if (t < 64) {
            float s = 0.f;
            #pragma unroll
            for (int ww = 0; ww < 16; ++ww) s += partial[ww * 64 + t];
            h1s[t] = s;
        }
    }
    __syncthreads();
    if (t < 8) {
        float a2 = c2_b[t];
        #pragma unroll 8
        for (int m = 0; m < 64; ++m) a2 += h1s[m] * c2_w[t * 64 + m];
        h2s[t] = a2;
    }
    __syncthreads();
    if (t == 0) {
        float a3 = c3_b[0];
        #pragma unroll
        for (int jj = 0; jj < 8; ++jj) a3 += h2s[jj] * c3_w[jj];
        out[b] = a3;
    }
}

extern "C" void kernel_launch(void* const* d_in, const int* in_sizes, int n_in,
                              void* d_out, int out_size, void* d_ws, size_t ws_size,
                              hipStream_t stream) {
    const float* rna    = (const float*)d_in[0];
    const float* drug   = (const float*)d_in[1];
    const float* lin1_w = (const float*)d_in[2];
    const float* lin1_b = (const float*)d_in[3];
    const float* lin2_w = (const float*)d_in[4];
    const float* lin2_b = (const float*)d_in[5];
    const float* chem_w = (const float*)d_in[6];
    const float* pos_w  = (const float*)d_in[7];
    const float* qkv_w  = (const float*)d_in[8];
    const float* qkv_b  = (const float*)d_in[9];
    const float* out_w  = (const float*)d_in[10];
    const float* out_b  = (const float*)d_in[11];
    const float* ln1_g  = (const float*)d_in[12];
    const float* ln1_b  = (const float*)d_in[13];
    const float* ff1_w  = (const float*)d_in[14];
    const float* ff1_b  = (const float*)d_in[15];
    const float* ff2_w  = (const float*)d_in[16];
    const float* ff2_b  = (const float*)d_in[17];
    const float* ln2_g  = (const float*)d_in[18];
    const float* ln2_b  = (const float*)d_in[19];
    const float* c1_w   = (const float*)d_in[20];
    const float* c1_b   = (const float*)d_in[21];
    const float* c2_w   = (const float*)d_in[22];
    const float* c2_b   = (const float*)d_in[23];
    const float* c3_w   = (const float*)d_in[24];
    const float* c3_b   = (const float*)d_in[25];
    float* ws  = (float*)d_ws;
    float* out = (float*)d_out;

    hipLaunchKernelGGL(prep_kernel, dim3(66), dim3(1024), 0, stream,
                       lin1_w, lin1_b, lin2_w, lin2_b, c1_w, c1_b, ff1_w, ff2_w,
                       chem_w, ws);
    hipLaunchKernelGGL(mega_kernel, dim3(BB), dim3(1024), 0, stream,
                       drug, ws + OFF_CHEMT, pos_w,
                       (const _Float16*)(ws + OFF_W1H), (const _Float16*)(ws + OFF_A2H),
                       ff1_b, qkv_w, qkv_b, out_w, out_b,
                       ln1_g, ln1_b, ff2_b, ln2_g, ln2_b,
                       rna, ws + OFF_WCATT, ws + OFF_BPRIME,
                       c2_w, c2_b, c3_w, c3_b, out);
}